// Round 1
// baseline (1813.335 us; speedup 1.0000x reference)
//
#include <hip/hip_runtime.h>
#include <math.h>

#define NN 100000
#define NE 3200000
#define FIN 128
#define HD 64
#define TOUT 16

// ---------------- degree / norm ----------------
__global__ __launch_bounds__(256) void k_deg(const int* __restrict__ dst, unsigned* __restrict__ deg) {
  int e = blockIdx.x * 256 + threadIdx.x;
  if (e < NE) atomicAdd(&deg[dst[e]], 1u);
}

__global__ __launch_bounds__(256) void k_dinv(const unsigned* __restrict__ deg, float* __restrict__ dinv) {
  int i = blockIdx.x * 256 + threadIdx.x;
  if (i < NN) dinv[i] = 1.0f / sqrtf((float)deg[i] + 1.0f);  // deg incl. self-loop >= 1
}

// ---------------- tiled vector GEMM: C[n,M] = A[n,K] @ W[K,M] ----------------
// 256 threads, 64-row x 64-col tile, 4x4 accum per thread. A staged in padded LDS.
template<int K>
__global__ __launch_bounds__(256) void k_gemm(const float* __restrict__ A, const float* __restrict__ W,
                                              float* __restrict__ C, int n, int M) {
  constexpr int AS = K + 4;  // pad to break bank aliasing across row groups
  __shared__ float As[64 * AS];
  int tid = threadIdx.x;
  int rowBase = blockIdx.x * 64;
  int colBase = blockIdx.y * 64;
  int nrows = n - rowBase; if (nrows > 64) nrows = 64;

  for (int idx = tid * 4; idx < 64 * K; idx += 1024) {
    int row = idx / K;
    int k = idx - row * K;
    float4 v = make_float4(0.f, 0.f, 0.f, 0.f);
    if (row < nrows) v = *(const float4*)(A + (size_t)(rowBase + row) * K + k);
    *(float4*)(&As[row * AS + k]) = v;
  }
  __syncthreads();

  int tx = tid & 15, ty = tid >> 4;
  int c0 = colBase + tx * 4;
  int r0 = ty * 4;
  float acc[4][4] = {{0.f}};

  for (int k = 0; k < K; ++k) {
    float4 wv = *(const float4*)(W + (size_t)k * M + c0);
    float wa[4] = {wv.x, wv.y, wv.z, wv.w};
#pragma unroll
    for (int i = 0; i < 4; ++i) {
      float a = As[(r0 + i) * AS + k];
#pragma unroll
      for (int j = 0; j < 4; ++j) acc[i][j] = fmaf(a, wa[j], acc[i][j]);
    }
  }

#pragma unroll
  for (int i = 0; i < 4; ++i) {
    int r = rowBase + r0 + i;
    if (r < n) {
      float4 o = make_float4(acc[i][0], acc[i][1], acc[i][2], acc[i][3]);
      *(float4*)(C + (size_t)r * M + c0) = o;
    }
  }
}

// ---------------- edge scatter: agg[dst] += dinv[src]*dinv[dst] * hw[src] ----------------
// one wave (64 lanes = 64 features) per edge, 4 edges per block
__global__ __launch_bounds__(256) void k_scatter(const float* __restrict__ hw, const int* __restrict__ src,
                                                 const int* __restrict__ dst, const float* __restrict__ dinv,
                                                 float* __restrict__ agg) {
  int e = blockIdx.x * 4 + (threadIdx.x >> 6);
  if (e >= NE) return;
  int lane = threadIdx.x & 63;
  int s = src[e], d = dst[e];
  float nrm = dinv[s] * dinv[d];
  float v = nrm * hw[(size_t)s * HD + lane];
  unsafeAtomicAdd(&agg[(size_t)d * HD + lane], v);
}

// ---------------- combine: h = relu(agg + dinv^2 * hw + b) (self-loop folded in) ----------------
__global__ __launch_bounds__(256) void k_combine(const float* __restrict__ agg, const float* __restrict__ hw,
                                                 const float* __restrict__ dinv, const float* __restrict__ b,
                                                 float* __restrict__ h) {
  int i = blockIdx.x * 256 + threadIdx.x;  // float4 index over [NN, 16 float4s]
  if (i >= NN * (HD / 4)) return;
  int row = i >> 4;
  float di = dinv[row];
  float sl = di * di;
  float4 a = ((const float4*)agg)[i];
  float4 w = ((const float4*)hw)[i];
  float4 bb = ((const float4*)b)[i & 15];
  float4 r;
  r.x = fmaxf(fmaf(sl, w.x, a.x) + bb.x, 0.f);
  r.y = fmaxf(fmaf(sl, w.y, a.y) + bb.y, 0.f);
  r.z = fmaxf(fmaf(sl, w.z, a.z) + bb.z, 0.f);
  r.w = fmaxf(fmaf(sl, w.w, a.w) + bb.w, 0.f);
  ((float4*)h)[i] = r;
}

// ---------------- transpose GRU weights: Wt[k*192+j] = w[j*64+k] ----------------
__global__ __launch_bounds__(256) void k_transpose(const float* __restrict__ w_ih, const float* __restrict__ w_hh,
                                                   float* __restrict__ WtIH, float* __restrict__ WtHH) {
  int t = blockIdx.x * 256 + threadIdx.x;
  if (t < 192 * 64) {
    int j = t >> 6, k = t & 63;
    WtIH[k * 192 + j] = w_ih[t];
    WtHH[k * 192 + j] = w_hh[t];
  }
}

// ---------------- GRU elementwise ----------------
__global__ __launch_bounds__(256) void k_gru(const float* __restrict__ GI, const float* __restrict__ GH,
                                             const float* __restrict__ bih, const float* __restrict__ bhh,
                                             const float* __restrict__ prev, float* __restrict__ hnew,
                                             int start, int cnt) {
  int t = blockIdx.x * 256 + threadIdx.x;
  if (t >= cnt * HD) return;
  int j = t & 63, il = t >> 6;
  int gb = il * 192 + j;
  float rg = GI[gb] + bih[j] + GH[gb] + bhh[j];
  rg = 1.f / (1.f + expf(-rg));
  float zg = GI[gb + 64] + bih[64 + j] + GH[gb + 64] + bhh[64 + j];
  zg = 1.f / (1.f + expf(-zg));
  float nc = tanhf(GI[gb + 128] + bih[128 + j] + rg * (GH[gb + 128] + bhh[128 + j]));
  float h0 = prev[(size_t)(start + il) * HD + j];
  hnew[(size_t)(start + il) * HD + j] = (1.f - zg) * nc + zg * h0;
}

// ---------------- readout: out[n,16] = hnew @ Wp + bp ----------------
__global__ __launch_bounds__(256) void k_readout(const float* __restrict__ hnew, const float* __restrict__ Wp,
                                                 const float* __restrict__ bp, float* __restrict__ out) {
  int t = blockIdx.x * 256 + threadIdx.x;
  if (t >= NN * TOUT) return;
  int col = t & 15;
  int i = t >> 4;
  const float* hr = hnew + (size_t)i * HD;
  float acc = bp[col];
#pragma unroll
  for (int k = 0; k < HD; ++k) acc = fmaf(hr[k], Wp[k * TOUT + col], acc);
  out[t] = acc;
}

extern "C" void kernel_launch(void* const* d_in, const int* in_sizes, int n_in,
                              void* d_out, int out_size, void* d_ws, size_t ws_size,
                              hipStream_t stream) {
  const float* x    = (const float*)d_in[0];
  const int*   ei   = (const int*)d_in[1];
  const float* prev = (const float*)d_in[2];
  const float* W1   = (const float*)d_in[3];
  const float* b1   = (const float*)d_in[4];
  const float* W2   = (const float*)d_in[5];
  const float* b2   = (const float*)d_in[6];
  const float* w_ih = (const float*)d_in[7];
  const float* w_hh = (const float*)d_in[8];
  const float* b_ih = (const float*)d_in[9];
  const float* b_hh = (const float*)d_in[10];
  const float* Wp   = (const float*)d_in[11];
  const float* bp   = (const float*)d_in[12];

  float* out  = (float*)d_out;                 // [NN,16]
  float* hnew = out + (size_t)NN * TOUT;       // [NN,64]

  char* ws = (char*)d_ws;
  float*    dinv = (float*)ws;                                  // NN floats
  unsigned* degI = (unsigned*)(ws + 400000);                    // NN uints
  float*    bufA = (float*)(ws + 800000);                       // NN*64
  float*    bufB = (float*)(ws + 800000 + 25600000);            // NN*64
  float*    bufC = (float*)(ws + 800000 + 2 * 25600000);        // NN*64
  float*    WtIH = (float*)(ws + 800000 + 3 * 25600000);        // 64*192
  float*    WtHH = (float*)(ws + 800000 + 3 * 25600000 + 49152);

  const int* srcA = ei;
  const int* dstA = ei + NE;

  // degrees + norm
  hipMemsetAsync(degI, 0, NN * sizeof(unsigned), stream);
  k_deg<<<(NE + 255) / 256, 256, 0, stream>>>(dstA, degI);
  k_dinv<<<(NN + 255) / 256, 256, 0, stream>>>(degI, dinv);

  // ---- GCN layer 1 ----
  {
    dim3 g((NN + 63) / 64, 1);
    k_gemm<FIN><<<g, 256, 0, stream>>>(x, W1, bufA, NN, HD);
  }
  hipMemsetAsync(bufB, 0, (size_t)NN * HD * sizeof(float), stream);
  k_scatter<<<(NE + 3) / 4, 256, 0, stream>>>(bufA, srcA, dstA, dinv, bufB);
  k_combine<<<(NN * (HD / 4) + 255) / 256, 256, 0, stream>>>(bufB, bufA, dinv, b1, bufC);

  // ---- GCN layer 2 ----
  {
    dim3 g((NN + 63) / 64, 1);
    k_gemm<HD><<<g, 256, 0, stream>>>(bufC, W2, bufA, NN, HD);
  }
  hipMemsetAsync(bufB, 0, (size_t)NN * HD * sizeof(float), stream);
  k_scatter<<<(NE + 3) / 4, 256, 0, stream>>>(bufA, srcA, dstA, dinv, bufB);
  k_combine<<<(NN * (HD / 4) + 255) / 256, 256, 0, stream>>>(bufB, bufA, dinv, b2, bufC);

  // ---- GRU (chunked so GI/GH [chunk,192] fit in bufA/bufB) ----
  k_transpose<<<(192 * 64 + 255) / 256, 256, 0, stream>>>(w_ih, w_hh, WtIH, WtHH);
  const int CH = 25000;
  for (int c = 0; c < 4; ++c) {
    int start = c * CH;
    dim3 g((CH + 63) / 64, 3);  // M=192 -> 3 column tiles
    k_gemm<HD><<<g, 256, 0, stream>>>(bufC + (size_t)start * HD, WtIH, bufA, CH, 192);
    k_gemm<HD><<<g, 256, 0, stream>>>(prev + (size_t)start * HD, WtHH, bufB, CH, 192);
    k_gru<<<(CH * HD + 255) / 256, 256, 0, stream>>>(bufA, bufB, b_ih, b_hh, prev, hnew, start, CH);
  }

  // ---- readout ----
  k_readout<<<(NN * TOUT + 255) / 256, 256, 0, stream>>>(hnew, Wp, bp, out);
}

// Round 2
// 878.799 us; speedup vs baseline: 2.0634x; 2.0634x over previous
//
#include <hip/hip_runtime.h>
#include <math.h>

#define NN 100000
#define NE 3200000
#define FIN 128
#define HD 64
#define TOUT 16
#define NB_SCAN ((NN + 255) / 256)   // 391

// ---------------- degree ----------------
__global__ __launch_bounds__(256) void k_deg(const int* __restrict__ dst, unsigned* __restrict__ deg) {
  int e = blockIdx.x * 256 + threadIdx.x;
  if (e < NE) atomicAdd(&deg[dst[e]], 1u);
}

__global__ __launch_bounds__(256) void k_dinv(const unsigned* __restrict__ deg, float* __restrict__ dinv) {
  int i = blockIdx.x * 256 + threadIdx.x;
  if (i < NN) dinv[i] = 1.0f / sqrtf((float)deg[i] + 1.0f);  // +1 self-loop
}

// ---------------- exclusive scan (3 phases) ----------------
__global__ __launch_bounds__(256) void k_scan_local(const unsigned* __restrict__ deg,
                                                    int* __restrict__ rowptr,
                                                    unsigned* __restrict__ blockSum) {
  __shared__ unsigned s[256];
  int t = threadIdx.x, i = blockIdx.x * 256 + t;
  unsigned v = (i < NN) ? deg[i] : 0u;
  s[t] = v;
  __syncthreads();
  for (int off = 1; off < 256; off <<= 1) {
    unsigned y = (t >= off) ? s[t - off] : 0u;
    __syncthreads();
    s[t] += y;
    __syncthreads();
  }
  if (i < NN) rowptr[i] = (int)(s[t] - v);          // local exclusive
  if (t == 255) blockSum[blockIdx.x] = s[255];
}

__global__ __launch_bounds__(512) void k_scan_block(unsigned* __restrict__ blockSum) {
  __shared__ unsigned s[512];
  int t = threadIdx.x;
  unsigned v = (t < NB_SCAN) ? blockSum[t] : 0u;
  s[t] = v;
  __syncthreads();
  for (int off = 1; off < 512; off <<= 1) {
    unsigned y = (t >= off) ? s[t - off] : 0u;
    __syncthreads();
    s[t] += y;
    __syncthreads();
  }
  if (t < NB_SCAN) blockSum[t] = s[t] - v;          // exclusive block offsets
}

__global__ __launch_bounds__(256) void k_scan_add(int* __restrict__ rowptr, const unsigned* __restrict__ blockSum,
                                                  int* __restrict__ cursor) {
  int i = blockIdx.x * 256 + threadIdx.x;
  if (i < NN) {
    int r = rowptr[i] + (int)blockSum[i >> 8];
    rowptr[i] = r;
    cursor[i] = r;
  }
  if (i == 0) rowptr[NN] = NE;
}

// ---------------- counting sort: csr_src[pos] = src, bucketed by dst ----------------
__global__ __launch_bounds__(256) void k_bucket(const int* __restrict__ src, const int* __restrict__ dst,
                                                int* __restrict__ cursor, int* __restrict__ csr_src) {
  int e = blockIdx.x * 256 + threadIdx.x;
  if (e >= NE) return;
  int d = dst[e];
  int p = atomicAdd(&cursor[d], 1);
  csr_src[p] = src[e];
}

// ---------------- tiled vector GEMM: C[n,M] = (A[n,K] @ W[K,M]) * (scale?scale[r]:1) ----------------
template<int K>
__global__ __launch_bounds__(256) void k_gemm(const float* __restrict__ A, const float* __restrict__ W,
                                              float* __restrict__ C, int n, int M,
                                              const float* __restrict__ scale) {
  constexpr int AS = K + 4;
  __shared__ float As[64 * AS];
  int tid = threadIdx.x;
  int rowBase = blockIdx.x * 64;
  int colBase = blockIdx.y * 64;
  int nrows = n - rowBase; if (nrows > 64) nrows = 64;

  for (int idx = tid * 4; idx < 64 * K; idx += 1024) {
    int row = idx / K;
    int k = idx - row * K;
    float4 v = make_float4(0.f, 0.f, 0.f, 0.f);
    if (row < nrows) v = *(const float4*)(A + (size_t)(rowBase + row) * K + k);
    *(float4*)(&As[row * AS + k]) = v;
  }
  __syncthreads();

  int tx = tid & 15, ty = tid >> 4;
  int c0 = colBase + tx * 4;
  int r0 = ty * 4;
  float acc[4][4] = {{0.f}};

  for (int k = 0; k < K; ++k) {
    float4 wv = *(const float4*)(W + (size_t)k * M + c0);
    float wa[4] = {wv.x, wv.y, wv.z, wv.w};
#pragma unroll
    for (int i = 0; i < 4; ++i) {
      float a = As[(r0 + i) * AS + k];
#pragma unroll
      for (int j = 0; j < 4; ++j) acc[i][j] = fmaf(a, wa[j], acc[i][j]);
    }
  }

#pragma unroll
  for (int i = 0; i < 4; ++i) {
    int r = rowBase + r0 + i;
    if (r < n) {
      float sc = scale ? scale[r] : 1.0f;
      float4 o = make_float4(acc[i][0] * sc, acc[i][1] * sc, acc[i][2] * sc, acc[i][3] * sc);
      *(float4*)(C + (size_t)r * M + c0) = o;
    }
  }
}

// ---------------- gather aggregation: h[d] = relu(dinv[d]*(hws[d] + sum_{e} hws[src_e]) + b) ----------------
// wave per node, lane per feature
__global__ __launch_bounds__(256) void k_gather(const float* __restrict__ hws, const int* __restrict__ rowptr,
                                                const int* __restrict__ csr_src, const float* __restrict__ dinv,
                                                const float* __restrict__ b, float* __restrict__ h) {
  int node = blockIdx.x * 4 + (threadIdx.x >> 6);
  if (node >= NN) return;
  int lane = threadIdx.x & 63;
  int beg = rowptr[node], end = rowptr[node + 1];
  float acc = hws[(size_t)node * HD + lane];       // self-loop term (already dinv[node]-scaled)
  for (int base = beg; base < end; base += 64) {
    int rem = end - base;
    int m = rem < 64 ? rem : 64;
    int myS = (lane < m) ? csr_src[base + lane] : 0;
    int i = 0;
    for (; i + 4 <= m; i += 4) {
      int s0 = __shfl(myS, i), s1 = __shfl(myS, i + 1), s2 = __shfl(myS, i + 2), s3 = __shfl(myS, i + 3);
      float v0 = hws[(size_t)s0 * HD + lane];
      float v1 = hws[(size_t)s1 * HD + lane];
      float v2 = hws[(size_t)s2 * HD + lane];
      float v3 = hws[(size_t)s3 * HD + lane];
      acc += (v0 + v1) + (v2 + v3);
    }
    for (; i < m; ++i) {
      int s = __shfl(myS, i);
      acc += hws[(size_t)s * HD + lane];
    }
  }
  h[(size_t)node * HD + lane] = fmaxf(fmaf(dinv[node], acc, b[lane]), 0.f);
}

// ---------------- transpose GRU weights ----------------
__global__ __launch_bounds__(256) void k_transpose(const float* __restrict__ w_ih, const float* __restrict__ w_hh,
                                                   float* __restrict__ WtIH, float* __restrict__ WtHH) {
  int t = blockIdx.x * 256 + threadIdx.x;
  if (t < 192 * 64) {
    int j = t >> 6, k = t & 63;
    WtIH[k * 192 + j] = w_ih[t];
    WtHH[k * 192 + j] = w_hh[t];
  }
}

// ---------------- GRU elementwise ----------------
__global__ __launch_bounds__(256) void k_gru(const float* __restrict__ GI, const float* __restrict__ GH,
                                             const float* __restrict__ bih, const float* __restrict__ bhh,
                                             const float* __restrict__ prev, float* __restrict__ hnew,
                                             int start, int cnt) {
  int t = blockIdx.x * 256 + threadIdx.x;
  if (t >= cnt * HD) return;
  int j = t & 63, il = t >> 6;
  int gb = il * 192 + j;
  float rg = GI[gb] + bih[j] + GH[gb] + bhh[j];
  rg = 1.f / (1.f + expf(-rg));
  float zg = GI[gb + 64] + bih[64 + j] + GH[gb + 64] + bhh[64 + j];
  zg = 1.f / (1.f + expf(-zg));
  float nc = tanhf(GI[gb + 128] + bih[128 + j] + rg * (GH[gb + 128] + bhh[128 + j]));
  float h0 = prev[(size_t)(start + il) * HD + j];
  hnew[(size_t)(start + il) * HD + j] = (1.f - zg) * nc + zg * h0;
}

// ---------------- readout ----------------
__global__ __launch_bounds__(256) void k_readout(const float* __restrict__ hnew, const float* __restrict__ Wp,
                                                 const float* __restrict__ bp, float* __restrict__ out) {
  int t = blockIdx.x * 256 + threadIdx.x;
  if (t >= NN * TOUT) return;
  int col = t & 15;
  int i = t >> 4;
  const float* hr = hnew + (size_t)i * HD;
  float acc = bp[col];
#pragma unroll
  for (int k = 0; k < HD; ++k) acc = fmaf(hr[k], Wp[k * TOUT + col], acc);
  out[t] = acc;
}

extern "C" void kernel_launch(void* const* d_in, const int* in_sizes, int n_in,
                              void* d_out, int out_size, void* d_ws, size_t ws_size,
                              hipStream_t stream) {
  const float* x    = (const float*)d_in[0];
  const int*   ei   = (const int*)d_in[1];
  const float* prev = (const float*)d_in[2];
  const float* W1   = (const float*)d_in[3];
  const float* b1   = (const float*)d_in[4];
  const float* W2   = (const float*)d_in[5];
  const float* b2   = (const float*)d_in[6];
  const float* w_ih = (const float*)d_in[7];
  const float* w_hh = (const float*)d_in[8];
  const float* b_ih = (const float*)d_in[9];
  const float* b_hh = (const float*)d_in[10];
  const float* Wp   = (const float*)d_in[11];
  const float* bp   = (const float*)d_in[12];

  float* out  = (float*)d_out;                 // [NN,16]
  float* hnew = out + (size_t)NN * TOUT;       // [NN,64]

  char* ws = (char*)d_ws;
  float*    dinv    = (float*)(ws + 0);                    // 400,000
  unsigned* degI    = (unsigned*)(ws + 400000);            // 400,000
  int*      rowptr  = (int*)(ws + 800000);                 // 400,064 (NN+1)
  int*      cursor  = (int*)(ws + 1200064);                // 400,000
  unsigned* blkSum  = (unsigned*)(ws + 1600064);           // 4,160
  int*      csr_src = (int*)(ws + 1604224);                // 12,800,000
  float*    bufA    = (float*)(ws + 14404608);             // 25,600,000
  float*    bufB    = (float*)(ws + 40004608);             // 25,600,000
  float*    bufC    = (float*)(ws + 65604608);             // 25,600,000
  float*    WtIH    = (float*)(ws + 91204608);             // 49,152
  float*    WtHH    = (float*)(ws + 91253760);             // 49,152

  const int* srcA = ei;
  const int* dstA = ei + NE;

  // ---- degree / norm / CSR build ----
  hipMemsetAsync(degI, 0, NN * sizeof(unsigned), stream);
  k_deg<<<(NE + 255) / 256, 256, 0, stream>>>(dstA, degI);
  k_dinv<<<(NN + 255) / 256, 256, 0, stream>>>(degI, dinv);
  k_scan_local<<<NB_SCAN, 256, 0, stream>>>(degI, rowptr, blkSum);
  k_scan_block<<<1, 512, 0, stream>>>(blkSum);
  k_scan_add<<<NB_SCAN, 256, 0, stream>>>(rowptr, blkSum, cursor);
  k_bucket<<<(NE + 255) / 256, 256, 0, stream>>>(srcA, dstA, cursor, csr_src);

  // ---- GCN layer 1 ----
  k_gemm<FIN><<<dim3((NN + 63) / 64, 1), 256, 0, stream>>>(x, W1, bufA, NN, HD, dinv);
  k_gather<<<(NN + 3) / 4, 256, 0, stream>>>(bufA, rowptr, csr_src, dinv, b1, bufC);

  // ---- GCN layer 2 ----
  k_gemm<HD><<<dim3((NN + 63) / 64, 1), 256, 0, stream>>>(bufC, W2, bufA, NN, HD, dinv);
  k_gather<<<(NN + 3) / 4, 256, 0, stream>>>(bufA, rowptr, csr_src, dinv, b2, bufC);

  // ---- GRU (chunked) ----
  k_transpose<<<(192 * 64 + 255) / 256, 256, 0, stream>>>(w_ih, w_hh, WtIH, WtHH);
  const int CH = 25000;
  for (int c = 0; c < 4; ++c) {
    int start = c * CH;
    dim3 g((CH + 63) / 64, 3);
    k_gemm<HD><<<g, 256, 0, stream>>>(bufC + (size_t)start * HD, WtIH, bufA, CH, 192, nullptr);
    k_gemm<HD><<<g, 256, 0, stream>>>(prev + (size_t)start * HD, WtHH, bufB, CH, 192, nullptr);
    k_gru<<<(CH * HD + 255) / 256, 256, 0, stream>>>(bufA, bufB, b_ih, b_hh, prev, hnew, start, CH);
  }

  // ---- readout ----
  k_readout<<<(NN * TOUT + 255) / 256, 256, 0, stream>>>(hnew, Wp, bp, out);
}